// Round 4
// baseline (10138.735 us; speedup 1.0000x reference)
//
#include <hip/hip_runtime.h>
#include <stdint.h>

// ---------------------------------------------------------------------------
// LstmAtt round 4: traffic-focused.
//  - X pre-converted to bf16; softmax_v stages X[b] in LDS once (3 heads reuse).
//  - gates GEMM 128x128 tiles (wave 64x64), two-pass fused LSTM epilogue.
//  - ping-pong act buffers (fixes intra-dispatch h read/write race).
//  - logits GEMM 64x64 tiles, b_att fused.
// Act row layout (KPAD=1184 halfs): [0..389]=v, [390..415]=0 pad, [416..1183]=h.
// ---------------------------------------------------------------------------

#define B_SZ   1024
#define LSEQ   128
#define DIN    130
#define HDIM   768
#define NFEAT  49
#define NPROJ  40
#define KPAD   1184
#define VOFF   416
#define NGATE  3072
#define KT_G   37      // KPAD/32
#define KT_L   24      // HDIM/32
#define XELEM  (LSEQ * DIN)   // 16640 halfs per sample

typedef unsigned short u16;
typedef __attribute__((ext_vector_type(8))) short short8;
typedef __attribute__((ext_vector_type(4))) float f32x4;

__device__ __forceinline__ u16 f2bf(float f) {
  unsigned int u = __float_as_uint(f);
  u += 0x7FFFu + ((u >> 16) & 1u);   // round-to-nearest-even
  return (u16)(u >> 16);
}
__device__ __forceinline__ float bf2f(u16 b) {
  return __uint_as_float(((unsigned int)b) << 16);
}
__device__ __forceinline__ void split_store(float x, u16* hi, u16* lo) {
  u16 h = f2bf(x);
  *hi = h;
  *lo = f2bf(x - bf2f(h));
}

// ---------------------------------------------------------------------------
// Logits GEMM: C[1024,384] = h[1024,768] @ Watt[384,768]^T + b_att, split-2 A.
// BM=BN=64, 256 thr (waves 2x2, wave tile 32x32). Grid (16,6)=96.
// ---------------------------------------------------------------------------
__global__ __launch_bounds__(256, 4) void gemm_logits(
    const u16* __restrict__ Ahi, const u16* __restrict__ Alo,
    const u16* __restrict__ Bh, const float* __restrict__ b_att,
    float* __restrict__ C)
{
  __shared__ __align__(16) u16 sAh[64 * 40];
  __shared__ __align__(16) u16 sAl[64 * 40];
  __shared__ __align__(16) u16 sBh[64 * 40];

  const int tid = threadIdx.x, lane = tid & 63, wid = tid >> 6;
  const int wm = (wid & 1) * 32, wn = (wid >> 1) * 32;
  const int lm = lane & 15, quad = lane >> 4;
  const int bm = blockIdx.x * 64, bn = blockIdx.y * 64;

  const int ar = tid >> 2, ac = (tid & 3) * 8;
  const size_t a_off = (size_t)(bm + ar) * KPAD + ac;
  const size_t b_off = (size_t)(bn + ar) * HDIM + ac;

  uint4 ph = *(const uint4*)(Ahi + a_off);
  uint4 pl = *(const uint4*)(Alo + a_off);
  uint4 pb = *(const uint4*)(Bh + b_off);

  f32x4 acc[2][2];
#pragma unroll
  for (int i = 0; i < 2; ++i)
#pragma unroll
    for (int j = 0; j < 2; ++j) acc[i][j] = (f32x4){0.f, 0.f, 0.f, 0.f};

  for (int kt = 0; kt < KT_L; ++kt) {
    *(uint4*)&sAh[ar * 40 + ac] = ph;
    *(uint4*)&sAl[ar * 40 + ac] = pl;
    *(uint4*)&sBh[ar * 40 + ac] = pb;
    __syncthreads();
    if (kt + 1 < KT_L) {
      const int k0 = (kt + 1) * 32;
      ph = *(const uint4*)(Ahi + a_off + k0);
      pl = *(const uint4*)(Alo + a_off + k0);
      pb = *(const uint4*)(Bh + b_off + k0);
    }
    short8 ah[2], al[2], bh[2];
#pragma unroll
    for (int mi = 0; mi < 2; ++mi) {
      ah[mi] = *(const short8*)&sAh[(wm + mi * 16 + lm) * 40 + quad * 8];
      al[mi] = *(const short8*)&sAl[(wm + mi * 16 + lm) * 40 + quad * 8];
    }
#pragma unroll
    for (int ni = 0; ni < 2; ++ni)
      bh[ni] = *(const short8*)&sBh[(wn + ni * 16 + lm) * 40 + quad * 8];
#pragma unroll
    for (int mi = 0; mi < 2; ++mi)
#pragma unroll
      for (int ni = 0; ni < 2; ++ni) {
        acc[mi][ni] = __builtin_amdgcn_mfma_f32_16x16x32_bf16(ah[mi], bh[ni], acc[mi][ni], 0, 0, 0);
        acc[mi][ni] = __builtin_amdgcn_mfma_f32_16x16x32_bf16(al[mi], bh[ni], acc[mi][ni], 0, 0, 0);
      }
    __syncthreads();
  }

#pragma unroll
  for (int mi = 0; mi < 2; ++mi)
#pragma unroll
    for (int ni = 0; ni < 2; ++ni) {
      const int col = bn + wn + ni * 16 + lm;
      const int row0 = bm + wm + mi * 16 + quad * 4;
      const float ba = b_att[col];
#pragma unroll
      for (int r = 0; r < 4; ++r)
        C[(size_t)(row0 + r) * 384 + col] = acc[mi][ni][r] + ba;
    }
}

// ---------------------------------------------------------------------------
// Gates GEMM + fused LSTM: BM=128 rows(samples) x BN=128 (4 gate-strips of 32 j).
// 256 thr, waves 2x2, wave tile 64x64 (FM=FN=4), split-2 A. Grid (8,24)=192.
// Reads act_rd (v+h of step t), writes h(t+1) into act_wr (ping-pong, race-free).
// Two-pass epilogue through a 64x132 fp32 LDS tile (union with staging).
// ---------------------------------------------------------------------------
__global__ __launch_bounds__(256, 3) void gemm_gates_lstm(
    const u16* __restrict__ Ahi, const u16* __restrict__ Alo,
    const u16* __restrict__ Wh,  const float* __restrict__ bsum,
    float* __restrict__ cst, float* __restrict__ hmax,
    u16* __restrict__ out_hi, u16* __restrict__ out_lo)
{
  __shared__ __align__(16) char smem[64 * 132 * 4];   // 33792 B
  u16* sAh = (u16*)smem;                   // 128*40 halfs = 10240 B
  u16* sAl = (u16*)(smem + 10240);
  u16* sBh = (u16*)(smem + 20480);
  float* tile = (float*)smem;              // epilogue: 64 x 132 fp32

  const int tid = threadIdx.x, lane = tid & 63, wid = tid >> 6;
  const int wm = (wid & 1) * 64, wn = (wid >> 1) * 64;
  const int lm = lane & 15, quad = lane >> 4;
  const int bm = blockIdx.x * 128, j0 = blockIdx.y * 32;

  const int ar = tid >> 2, ac = (tid & 3) * 8;   // ar in [0,64)
  const size_t a_off0 = (size_t)(bm + ar) * KPAD + ac;
  const size_t a_off1 = (size_t)(bm + 64 + ar) * KPAD + ac;
  const int n0 = (ar >> 5) * HDIM + j0 + (ar & 31);
  const int n1 = (2 + (ar >> 5)) * HDIM + j0 + (ar & 31);
  const size_t b_off0 = (size_t)n0 * KPAD + ac;
  const size_t b_off1 = (size_t)n1 * KPAD + ac;

  uint4 pah0 = *(const uint4*)(Ahi + a_off0);
  uint4 pah1 = *(const uint4*)(Ahi + a_off1);
  uint4 pal0 = *(const uint4*)(Alo + a_off0);
  uint4 pal1 = *(const uint4*)(Alo + a_off1);
  uint4 pb0  = *(const uint4*)(Wh + b_off0);
  uint4 pb1  = *(const uint4*)(Wh + b_off1);

  f32x4 acc[4][4];
#pragma unroll
  for (int mi = 0; mi < 4; ++mi)
#pragma unroll
    for (int ni = 0; ni < 4; ++ni) acc[mi][ni] = (f32x4){0.f, 0.f, 0.f, 0.f};

  for (int kt = 0; kt < KT_G; ++kt) {
    *(uint4*)&sAh[ar * 40 + ac]        = pah0;
    *(uint4*)&sAh[(64 + ar) * 40 + ac] = pah1;
    *(uint4*)&sAl[ar * 40 + ac]        = pal0;
    *(uint4*)&sAl[(64 + ar) * 40 + ac] = pal1;
    *(uint4*)&sBh[ar * 40 + ac]        = pb0;
    *(uint4*)&sBh[(64 + ar) * 40 + ac] = pb1;
    __syncthreads();
    if (kt + 1 < KT_G) {
      const int k0 = (kt + 1) * 32;
      pah0 = *(const uint4*)(Ahi + a_off0 + k0);
      pah1 = *(const uint4*)(Ahi + a_off1 + k0);
      pal0 = *(const uint4*)(Alo + a_off0 + k0);
      pal1 = *(const uint4*)(Alo + a_off1 + k0);
      pb0  = *(const uint4*)(Wh + b_off0 + k0);
      pb1  = *(const uint4*)(Wh + b_off1 + k0);
    }
    short8 ah[4], al[4], bh[4];
#pragma unroll
    for (int mi = 0; mi < 4; ++mi) {
      ah[mi] = *(const short8*)&sAh[(wm + mi * 16 + lm) * 40 + quad * 8];
      al[mi] = *(const short8*)&sAl[(wm + mi * 16 + lm) * 40 + quad * 8];
    }
#pragma unroll
    for (int ni = 0; ni < 4; ++ni)
      bh[ni] = *(const short8*)&sBh[(wn + ni * 16 + lm) * 40 + quad * 8];
#pragma unroll
    for (int mi = 0; mi < 4; ++mi)
#pragma unroll
      for (int ni = 0; ni < 4; ++ni) {
        acc[mi][ni] = __builtin_amdgcn_mfma_f32_16x16x32_bf16(ah[mi], bh[ni], acc[mi][ni], 0, 0, 0);
        acc[mi][ni] = __builtin_amdgcn_mfma_f32_16x16x32_bf16(al[mi], bh[ni], acc[mi][ni], 0, 0, 0);
      }
    __syncthreads();
  }

  // ---- two-pass epilogue: 64 rows at a time through the LDS tile ----
#pragma unroll
  for (int p = 0; p < 2; ++p) {
    if ((wid & 1) == p) {
#pragma unroll
      for (int mi = 0; mi < 4; ++mi)
#pragma unroll
        for (int ni = 0; ni < 4; ++ni) {
          const int c = wn + ni * 16 + lm;
          const int rbase = mi * 16 + quad * 4;   // local (wm removed by pass)
#pragma unroll
          for (int r = 0; r < 4; ++r)
            tile[(rbase + r) * 132 + c] = acc[mi][ni][r];
        }
    }
    __syncthreads();
#pragma unroll
    for (int i = 0; i < 8; ++i) {
      const int lin = tid + 256 * i;      // 64 rows x 32 j
      const int row = lin >> 5, jj = lin & 31;
      const int b = bm + p * 64 + row, j = j0 + jj;
      const float* tr = tile + row * 132;
      const float pi = tr[jj]      + bsum[j];
      const float pf = tr[32 + jj] + bsum[HDIM + j];
      const float pg = tr[64 + jj] + bsum[2 * HDIM + j];
      const float po = tr[96 + jj] + bsum[3 * HDIM + j];
      const float si = 1.f / (1.f + expf(-pi));
      const float sf = 1.f / (1.f + expf(-pf));
      const float so = 1.f / (1.f + expf(-po));
      const size_t cidx = (size_t)b * HDIM + j;
      const float cn = sf * cst[cidx] + si * tanhf(pg);
      const float hn = so * tanhf(cn);
      cst[cidx] = cn;
      hmax[cidx] = fmaxf(hmax[cidx], hn);
      const size_t o = (size_t)b * KPAD + VOFF + j;
      split_store(hn, &out_hi[o], &out_lo[o]);
    }
    __syncthreads();
  }
}

// ---------------------------------------------------------------------------
// softmax_v v2: X[b] (bf16) staged to LDS once, reused by all 3 heads.
// logits already include b_att. Writes v into act (hi/lo) of the READ buffer.
// ---------------------------------------------------------------------------
__global__ __launch_bounds__(512) void softmax_v(
    const float* __restrict__ logits,   // [B][384], bias included
    const u16* __restrict__ Xb,         // [B][16640] bf16
    u16* __restrict__ act_hi, u16* __restrict__ act_lo)
{
  const int b = blockIdx.x;
  const int t = threadIdx.x;
  __shared__ __align__(16) u16 sX[XELEM];   // 33280 B
  __shared__ float s_val[384];
  __shared__ float s_red[512];

  // stage X[b]: 2080 uint4 chunks
  {
    const uint4* src = (const uint4*)(Xb + (size_t)b * XELEM);
    uint4* dst = (uint4*)sX;
    dst[t]        = src[t];
    dst[t + 512]  = src[t + 512];
    dst[t + 1024] = src[t + 1024];
    dst[t + 1536] = src[t + 1536];
    if (t < 32) dst[t + 2048] = src[t + 2048];
  }

  float x = -3.4e38f;
  if (t < 384) {
    x = logits[(size_t)b * 384 + t];
    s_val[t] = x;
  }
  s_red[t] = x;
  __syncthreads();
#pragma unroll
  for (int off = 64; off > 0; off >>= 1) {
    float other = -3.4e38f;
    if ((t & 127) < off) other = s_red[t + off];
    __syncthreads();
    if ((t & 127) < off) s_red[t] = fmaxf(s_red[t], other);
    __syncthreads();
  }
  const float mk = s_red[t & ~127];
  __syncthreads();

  float e = 0.f;
  if (t < 384) e = expf(s_val[t] - mk);
  s_red[t] = e;
  __syncthreads();
#pragma unroll
  for (int off = 64; off > 0; off >>= 1) {
    float other = 0.f;
    if ((t & 127) < off) other = s_red[t + off];
    __syncthreads();
    if ((t & 127) < off) s_red[t] += other;
    __syncthreads();
  }
  const float sk = s_red[t & ~127];
  if (t < 384) s_val[t] = e / sk;     // normalized alp
  __syncthreads();

  if (t < 390) {
    const int k = t / 130;
    const int d = t - k * 130;
    const u16* __restrict__ xp = sX + d;
    const float* __restrict__ ak = s_val + (k << 7);
    float acc = 0.f;
#pragma unroll 8
    for (int l = 0; l < LSEQ; ++l) acc += ak[l] * bf2f(xp[l * DIN]);
    const size_t o = (size_t)b * KPAD + t;
    split_store(acc, &act_hi[o], &act_lo[o]);
  }
}

// ---------------------------------------------------------------------------
// Final head (once per call).
// ---------------------------------------------------------------------------
__global__ __launch_bounds__(64) void final_head(
    const float* __restrict__ hmax, const float* __restrict__ Fe,
    const float* __restrict__ W_d1, const float* __restrict__ b_d1,
    const float* __restrict__ W_r,  const float* __restrict__ b_r,
    const float* __restrict__ W_a,
    const float* __restrict__ W_d2, const float* __restrict__ b_d2,
    float* __restrict__ out)
{
  const int b = blockIdx.x;
  const int t = threadIdx.x;
  __shared__ float sx[HDIM];
  __shared__ float sy[NFEAT];
  __shared__ float sr1[NPROJ], sr2[NPROJ];
  __shared__ float sa[2];

  for (int i = t; i < HDIM; i += 64) sx[i] = hmax[(size_t)b * HDIM + i];
  __syncthreads();

  if (t < NFEAT) {
    float acc = b_d1[t];
    const float* w = W_d1 + (size_t)t * HDIM;
    for (int i = 0; i < HDIM; ++i) acc += sx[i] * w[i];
    sy[t] = fmaxf(acc, 0.f);
  }
  __syncthreads();

  if (t < NPROJ) {
    float a1 = b_r[t], a2 = b_r[t];
    const float* w  = W_r + (size_t)t * NFEAT;
    const float* fe = Fe + (size_t)b * NFEAT;
    for (int i = 0; i < NFEAT; ++i) { a1 += sy[i] * w[i]; a2 += fe[i] * w[i]; }
    sr1[t] = (a1 > 0.f) ? a1 : 0.01f * a1;
    sr2[t] = (a2 > 0.f) ? a2 : 0.01f * a2;
  }
  __syncthreads();

  if (t == 0) {
    float a1 = 0.f, a2 = 0.f;
    for (int p = 0; p < NPROJ; ++p) {
      a1 += tanhf(sr1[p]) * W_a[p];
      a2 += tanhf(sr2[p]) * W_a[p];
    }
    const float mx = fmaxf(a1, a2);
    const float e1 = expf(a1 - mx), e2 = expf(a2 - mx);
    sa[0] = e1 / (e1 + e2);
    sa[1] = e2 / (e1 + e2);
  }
  __syncthreads();

  if (t < 2) {
    float acc = b_d2[t];
    const float* w = W_d2 + (size_t)t * NPROJ;
    for (int p = 0; p < NPROJ; ++p) {
      float s = sa[0] * sr1[p] + sa[1] * sr2[p];
      s = fmaxf(s, 0.f);
      acc += s * w[p];
    }
    out[(size_t)b * 2 + t] = acc;
  }
}

// ---------------------------------------------------------------------------
// Setup kernels (run every launch).
// ---------------------------------------------------------------------------
__global__ __launch_bounds__(256) void pack_w(
    const float* __restrict__ W_ih, const float* __restrict__ W_hh,
    const float* __restrict__ b_ih, const float* __restrict__ b_hh,
    u16* __restrict__ hi, float* __restrict__ bsum)
{
  const int idx = blockIdx.x * 256 + threadIdx.x;
  if (idx >= NGATE * KPAD) return;
  const int n = idx / KPAD;
  const int k = idx - n * KPAD;
  float v = 0.f;
  if (k < 3 * DIN)       v = W_ih[(size_t)n * (3 * DIN) + k];
  else if (k >= VOFF)    v = W_hh[(size_t)n * HDIM + (k - VOFF)];
  hi[idx] = f2bf(v);
  if (k == 0) bsum[n] = b_ih[n] + b_hh[n];
}

__global__ __launch_bounds__(256) void pack_watt(
    const float* __restrict__ W_att,   // [3][H][L]
    u16* __restrict__ hi)
{
  const int idx = blockIdx.x * 256 + threadIdx.x;   // [384][768]
  if (idx >= 384 * HDIM) return;
  const int n = idx / HDIM;          // n = k*128 + l
  const int h = idx - n * HDIM;
  const int katt = n >> 7;
  const int l = n & 127;
  hi[idx] = f2bf(W_att[((size_t)katt * HDIM + h) * LSEQ + l]);
}

__global__ __launch_bounds__(256) void pack_x(
    const float* __restrict__ X, u16* __restrict__ Xb)
{
  const int idx = blockIdx.x * 256 + threadIdx.x;   // per 4 floats
  const float4 v = ((const float4*)X)[idx];
  ushort4 o;
  o.x = f2bf(v.x); o.y = f2bf(v.y); o.z = f2bf(v.z); o.w = f2bf(v.w);
  ((ushort4*)Xb)[idx] = o;
}

__global__ __launch_bounds__(256) void init_state(
    u16* __restrict__ a0h, u16* __restrict__ a0l,
    u16* __restrict__ a1h, u16* __restrict__ a1l,
    float* __restrict__ cst, float* __restrict__ hmax)
{
  const int idx = blockIdx.x * 256 + threadIdx.x;
  if (idx < B_SZ * KPAD) { a0h[idx] = 0; a0l[idx] = 0; a1h[idx] = 0; a1l[idx] = 0; }
  if (idx < B_SZ * HDIM) { cst[idx] = 0.f; hmax[idx] = -3.4e38f; }
}

// ---------------------------------------------------------------------------
extern "C" void kernel_launch(void* const* d_in, const int* in_sizes, int n_in,
                              void* d_out, int out_size, void* d_ws, size_t ws_size,
                              hipStream_t stream) {
  const float* X     = (const float*)d_in[0];
  const float* Fe    = (const float*)d_in[1];
  const float* W_att = (const float*)d_in[2];
  const float* b_att = (const float*)d_in[3];
  const float* W_ih  = (const float*)d_in[4];
  const float* W_hh  = (const float*)d_in[5];
  const float* b_ih  = (const float*)d_in[6];
  const float* b_hh  = (const float*)d_in[7];
  const float* W_d1  = (const float*)d_in[8];
  const float* b_d1  = (const float*)d_in[9];
  const float* W_r   = (const float*)d_in[10];
  const float* b_r   = (const float*)d_in[11];
  const float* W_a   = (const float*)d_in[12];
  const float* W_d2  = (const float*)d_in[13];
  const float* b_d2  = (const float*)d_in[14];
  float* out = (float*)d_out;

  char* base = (char*)d_ws;
  size_t off = 0;
  auto alloc = [&](size_t nbytes) -> void* {
    void* p = base + off;
    off = (off + nbytes + 255) & ~(size_t)255;
    return p;
  };
  u16* act0_hi = (u16*)alloc((size_t)B_SZ * KPAD * 2);
  u16* act0_lo = (u16*)alloc((size_t)B_SZ * KPAD * 2);
  u16* act1_hi = (u16*)alloc((size_t)B_SZ * KPAD * 2);
  u16* act1_lo = (u16*)alloc((size_t)B_SZ * KPAD * 2);
  u16* wcat_hi = (u16*)alloc((size_t)NGATE * KPAD * 2);
  u16* watt_hi = (u16*)alloc((size_t)384 * HDIM * 2);
  u16* xb16    = (u16*)alloc((size_t)B_SZ * XELEM * 2);
  float* bsum  = (float*)alloc((size_t)NGATE * 4);
  float* logits = (float*)alloc((size_t)B_SZ * 384 * 4);
  float* cst    = (float*)alloc((size_t)B_SZ * HDIM * 4);
  float* hmax   = (float*)alloc((size_t)B_SZ * HDIM * 4);

  pack_w<<<(NGATE * KPAD + 255) / 256, 256, 0, stream>>>(W_ih, W_hh, b_ih, b_hh, wcat_hi, bsum);
  pack_watt<<<(384 * HDIM + 255) / 256, 256, 0, stream>>>(W_att, watt_hi);
  pack_x<<<(B_SZ * XELEM / 4) / 256, 256, 0, stream>>>(X, xb16);
  init_state<<<(B_SZ * KPAD + 255) / 256, 256, 0, stream>>>(act0_hi, act0_lo, act1_hi, act1_lo, cst, hmax);

  u16 *rd_hi = act0_hi, *rd_lo = act0_lo, *wr_hi = act1_hi, *wr_lo = act1_lo;
  for (int step = 0; step < LSEQ; ++step) {
    gemm_logits<<<dim3(B_SZ / 64, 384 / 64), 256, 0, stream>>>(
        rd_hi + VOFF, rd_lo + VOFF, watt_hi, b_att, logits);
    softmax_v<<<B_SZ, 512, 0, stream>>>(logits, xb16, rd_hi, rd_lo);
    gemm_gates_lstm<<<dim3(B_SZ / 128, NGATE / 128), 256, 0, stream>>>(
        rd_hi, rd_lo, wcat_hi, bsum, cst, hmax, wr_hi, wr_lo);
    u16* th = rd_hi; rd_hi = wr_hi; wr_hi = th;
    u16* tl = rd_lo; rd_lo = wr_lo; wr_lo = tl;
  }

  final_head<<<B_SZ, 64, 0, stream>>>(hmax, Fe, W_d1, b_d1, W_r, b_r, W_a, W_d2, b_d2, out);
}

// Round 5
// 6519.429 us; speedup vs baseline: 1.5552x; 1.5552x over previous
//
#include <hip/hip_runtime.h>
#include <stdint.h>

// ---------------------------------------------------------------------------
// LstmAtt round 5: occupancy-focused.
//  - gates GEMM: 64x128 tile (FM=2,FN=4, no spill) + split-K=2 -> 768 blocks,
//    partials g0/g1, separate lstm_update does sum + pointwise.
//  - logits GEMM: 32x64 tile + split-K=2 -> 384 blocks; sum folded into softmax.
//  - softmax_v: X stored transposed (XT[b][d][l] bf16), LDS-staged with XOR
//    swizzle; v-loop uses vector ds_read_b128 (was 128 scalar u16 reads).
// Act row layout (KPAD=1184 halfs): [0..389]=v, [390..415]=0 pad, [416..1183]=h.
// ---------------------------------------------------------------------------

#define B_SZ   1024
#define LSEQ   128
#define DIN    130
#define HDIM   768
#define NFEAT  49
#define NPROJ  40
#define KPAD   1184
#define VOFF   416
#define NGATE  3072
#define XELEM  (LSEQ * DIN)   // 16640

typedef unsigned short u16;
typedef __attribute__((ext_vector_type(8))) short short8;
typedef __attribute__((ext_vector_type(4))) float f32x4;

__device__ __forceinline__ u16 f2bf(float f) {
  unsigned int u = __float_as_uint(f);
  u += 0x7FFFu + ((u >> 16) & 1u);
  return (u16)(u >> 16);
}
__device__ __forceinline__ float bf2f(u16 b) {
  return __uint_as_float(((unsigned int)b) << 16);
}
__device__ __forceinline__ void split_store(float x, u16* hi, u16* lo) {
  u16 h = f2bf(x);
  *hi = h;
  *lo = f2bf(x - bf2f(h));
}

// ---------------------------------------------------------------------------
// Logits GEMM, split-K=2: Cpart[kh][1024,384] = h[1024, kh-half of 768] @ W^T.
// BM=32, BN=64, 256 thr (waves 2x2: wave tile 16x32). Grid (32,6,2)=384.
// ---------------------------------------------------------------------------
__global__ __launch_bounds__(256, 4) void gemm_logits_k(
    const u16* __restrict__ Ahi, const u16* __restrict__ Alo,
    const u16* __restrict__ Bh, float* __restrict__ Cp)
{
  __shared__ __align__(16) u16 sAh[32 * 40];
  __shared__ __align__(16) u16 sAl[32 * 40];
  __shared__ __align__(16) u16 sBh[64 * 40];

  const int tid = threadIdx.x, lane = tid & 63, wid = tid >> 6;
  const int wm = (wid & 1) * 16, wn = (wid >> 1) * 32;
  const int lm = lane & 15, quad = lane >> 4;
  const int bm = blockIdx.x * 32, bn = blockIdx.y * 64;
  const int kh = blockIdx.z;
  const int kbase = kh * 384;            // halfs
  float* __restrict__ C = Cp + (size_t)kh * B_SZ * 384;

  const bool aload = tid < 128;
  const int ar = tid >> 2, ac = (tid & 3) * 8;
  const size_t a_off = (size_t)(bm + ar) * KPAD + kbase + ac;
  const size_t b_off = (size_t)(bn + ar) * HDIM + kbase + ac;

  uint4 ph, pl, pb;
  if (aload) {
    ph = *(const uint4*)(Ahi + a_off);
    pl = *(const uint4*)(Alo + a_off);
  }
  pb = *(const uint4*)(Bh + b_off);

  f32x4 acc0 = {0.f, 0.f, 0.f, 0.f}, acc1 = {0.f, 0.f, 0.f, 0.f};

  for (int kt = 0; kt < 12; ++kt) {
    if (aload) {
      *(uint4*)&sAh[ar * 40 + ac] = ph;
      *(uint4*)&sAl[ar * 40 + ac] = pl;
    }
    *(uint4*)&sBh[ar * 40 + ac] = pb;
    __syncthreads();
    if (kt + 1 < 12) {
      const int k0 = (kt + 1) * 32;
      if (aload) {
        ph = *(const uint4*)(Ahi + a_off + k0);
        pl = *(const uint4*)(Alo + a_off + k0);
      }
      pb = *(const uint4*)(Bh + b_off + k0);
    }
    const short8 ah = *(const short8*)&sAh[(wm + lm) * 40 + quad * 8];
    const short8 al = *(const short8*)&sAl[(wm + lm) * 40 + quad * 8];
    const short8 b0 = *(const short8*)&sBh[(wn + lm) * 40 + quad * 8];
    const short8 b1 = *(const short8*)&sBh[(wn + 16 + lm) * 40 + quad * 8];
    acc0 = __builtin_amdgcn_mfma_f32_16x16x32_bf16(ah, b0, acc0, 0, 0, 0);
    acc0 = __builtin_amdgcn_mfma_f32_16x16x32_bf16(al, b0, acc0, 0, 0, 0);
    acc1 = __builtin_amdgcn_mfma_f32_16x16x32_bf16(ah, b1, acc1, 0, 0, 0);
    acc1 = __builtin_amdgcn_mfma_f32_16x16x32_bf16(al, b1, acc1, 0, 0, 0);
    __syncthreads();
  }

  const int col = bn + wn + lm;
  const int row0 = bm + wm + quad * 4;
#pragma unroll
  for (int r = 0; r < 4; ++r) {
    C[(size_t)(row0 + r) * 384 + col]      = acc0[r];
    C[(size_t)(row0 + r) * 384 + col + 16] = acc1[r];
  }
}

// ---------------------------------------------------------------------------
// Gates GEMM, split-K=2: Gpart[kh][1024,3072] partial. BM=64, BN=128, 256 thr
// (waves 2x2: wave tile 32x64, FM=2, FN=4 — proven no-spill shape).
// Grid (16,24,2)=768 blocks (~3/CU). kh=0: ktiles [0,19); kh=1: [19,37).
// ---------------------------------------------------------------------------
__global__ __launch_bounds__(256, 3) void gemm_gates_k(
    const u16* __restrict__ Ahi, const u16* __restrict__ Alo,
    const u16* __restrict__ Wh,  float* __restrict__ Gp)
{
  __shared__ __align__(16) u16 sAh[64 * 40];
  __shared__ __align__(16) u16 sAl[64 * 40];
  __shared__ __align__(16) u16 sBh[128 * 40];

  const int tid = threadIdx.x, lane = tid & 63, wid = tid >> 6;
  const int wm = (wid & 1) * 32, wn = (wid >> 1) * 64;
  const int lm = lane & 15, quad = lane >> 4;
  const int bm = blockIdx.x * 64, j0 = blockIdx.y * 128;
  const int kh = blockIdx.z;
  const int kn = kh ? 18 : 19;
  const int kbase = kh * 19 * 32;        // halfs
  float* __restrict__ C = Gp + (size_t)kh * B_SZ * NGATE;

  const int ar = tid >> 2, ac = (tid & 3) * 8;   // ar in [0,64)
  const size_t a_off  = (size_t)(bm + ar) * KPAD + kbase + ac;
  const size_t b_off0 = (size_t)(j0 + ar) * KPAD + kbase + ac;
  const size_t b_off1 = (size_t)(j0 + 64 + ar) * KPAD + kbase + ac;

  uint4 ph  = *(const uint4*)(Ahi + a_off);
  uint4 pl  = *(const uint4*)(Alo + a_off);
  uint4 pb0 = *(const uint4*)(Wh + b_off0);
  uint4 pb1 = *(const uint4*)(Wh + b_off1);

  f32x4 acc[2][4];
#pragma unroll
  for (int mi = 0; mi < 2; ++mi)
#pragma unroll
    for (int ni = 0; ni < 4; ++ni) acc[mi][ni] = (f32x4){0.f, 0.f, 0.f, 0.f};

  for (int kt = 0; kt < kn; ++kt) {
    *(uint4*)&sAh[ar * 40 + ac]        = ph;
    *(uint4*)&sAl[ar * 40 + ac]        = pl;
    *(uint4*)&sBh[ar * 40 + ac]        = pb0;
    *(uint4*)&sBh[(64 + ar) * 40 + ac] = pb1;
    __syncthreads();
    if (kt + 1 < kn) {
      const int k0 = (kt + 1) * 32;
      ph  = *(const uint4*)(Ahi + a_off + k0);
      pl  = *(const uint4*)(Alo + a_off + k0);
      pb0 = *(const uint4*)(Wh + b_off0 + k0);
      pb1 = *(const uint4*)(Wh + b_off1 + k0);
    }
    short8 ah[2], al[2], bh[4];
#pragma unroll
    for (int mi = 0; mi < 2; ++mi) {
      ah[mi] = *(const short8*)&sAh[(wm + mi * 16 + lm) * 40 + quad * 8];
      al[mi] = *(const short8*)&sAl[(wm + mi * 16 + lm) * 40 + quad * 8];
    }
#pragma unroll
    for (int ni = 0; ni < 4; ++ni)
      bh[ni] = *(const short8*)&sBh[(wn + ni * 16 + lm) * 40 + quad * 8];
#pragma unroll
    for (int mi = 0; mi < 2; ++mi)
#pragma unroll
      for (int ni = 0; ni < 4; ++ni) {
        acc[mi][ni] = __builtin_amdgcn_mfma_f32_16x16x32_bf16(ah[mi], bh[ni], acc[mi][ni], 0, 0, 0);
        acc[mi][ni] = __builtin_amdgcn_mfma_f32_16x16x32_bf16(al[mi], bh[ni], acc[mi][ni], 0, 0, 0);
      }
    __syncthreads();
  }

#pragma unroll
  for (int mi = 0; mi < 2; ++mi)
#pragma unroll
    for (int ni = 0; ni < 4; ++ni) {
      const int col = j0 + wn + ni * 16 + lm;
      const int row0 = bm + wm + mi * 16 + quad * 4;
#pragma unroll
      for (int r = 0; r < 4; ++r)
        C[(size_t)(row0 + r) * NGATE + col] = acc[mi][ni][r];
    }
}

// ---------------------------------------------------------------------------
// LSTM pointwise: g0+g1 partials + bsum -> c,h; running max; h -> act wr.
// ---------------------------------------------------------------------------
__global__ __launch_bounds__(256) void lstm_update(
    const float* __restrict__ g0, const float* __restrict__ g1,
    const float* __restrict__ bsum,
    float* __restrict__ cst, float* __restrict__ hmax,
    u16* __restrict__ out_hi, u16* __restrict__ out_lo)
{
  const int idx = blockIdx.x * 256 + threadIdx.x;       // B*H
  const int b = idx / HDIM;
  const int j = idx - b * HDIM;
  const size_t o0 = (size_t)b * NGATE + j;
  const float pi = g0[o0]              + g1[o0]              + bsum[j];
  const float pf = g0[o0 + HDIM]       + g1[o0 + HDIM]       + bsum[HDIM + j];
  const float pg = g0[o0 + 2 * HDIM]   + g1[o0 + 2 * HDIM]   + bsum[2 * HDIM + j];
  const float po = g0[o0 + 3 * HDIM]   + g1[o0 + 3 * HDIM]   + bsum[3 * HDIM + j];
  const float si = 1.f / (1.f + expf(-pi));
  const float sf = 1.f / (1.f + expf(-pf));
  const float so = 1.f / (1.f + expf(-po));
  const float cn = sf * cst[idx] + si * tanhf(pg);
  const float hn = so * tanhf(cn);
  cst[idx] = cn;
  hmax[idx] = fmaxf(hmax[idx], hn);
  const size_t o = (size_t)b * KPAD + VOFF + j;
  split_store(hn, &out_hi[o], &out_lo[o]);
}

// ---------------------------------------------------------------------------
// softmax_v v3: logits = l0+l1+b_att; softmax per head; v = alp @ X via
// XT[b][d][l] staged to LDS with XOR-block swizzle -> vector ds_read_b128.
// ---------------------------------------------------------------------------
__global__ __launch_bounds__(512, 4) void softmax_v(
    const float* __restrict__ l0, const float* __restrict__ l1,
    const float* __restrict__ b_att,
    const u16* __restrict__ XT,          // [B][130][128] bf16
    u16* __restrict__ act_hi, u16* __restrict__ act_lo)
{
  const int b = blockIdx.x;
  const int t = threadIdx.x;
  __shared__ __align__(16) u16 sXT[XELEM];   // swizzled [130][128]
  __shared__ float s_val[384];
  __shared__ float s_red[512];

  // stage XT[b] with block-XOR swizzle: uint4 i -> (d=i>>4, blk=i&15),
  // stored at uint4 index d*16 + (blk ^ (d&7)).
  {
    const uint4* src = (const uint4*)(XT + (size_t)b * XELEM);
    uint4* dst = (uint4*)sXT;
#pragma unroll
    for (int rep = 0; rep < 4; ++rep) {
      const int i = t + rep * 512;       // 0..2047
      const int d = i >> 4, blk = i & 15;
      dst[d * 16 + (blk ^ (d & 7))] = src[i];
    }
    if (t < 32) {
      const int i = 2048 + t;
      const int d = i >> 4, blk = i & 15;
      dst[d * 16 + (blk ^ (d & 7))] = src[i];
    }
  }

  float x = -3.4e38f;
  if (t < 384) {
    x = l0[(size_t)b * 384 + t] + l1[(size_t)b * 384 + t] + b_att[t];
    s_val[t] = x;
  }
  s_red[t] = x;
  __syncthreads();
#pragma unroll
  for (int off = 64; off > 0; off >>= 1) {
    float other = -3.4e38f;
    if ((t & 127) < off) other = s_red[t + off];
    __syncthreads();
    if ((t & 127) < off) s_red[t] = fmaxf(s_red[t], other);
    __syncthreads();
  }
  const float mk = s_red[t & ~127];
  __syncthreads();

  float e = 0.f;
  if (t < 384) e = expf(s_val[t] - mk);
  s_red[t] = e;
  __syncthreads();
#pragma unroll
  for (int off = 64; off > 0; off >>= 1) {
    float other = 0.f;
    if ((t & 127) < off) other = s_red[t + off];
    __syncthreads();
    if ((t & 127) < off) s_red[t] += other;
    __syncthreads();
  }
  const float sk = s_red[t & ~127];
  if (t < 384) s_val[t] = e / sk;     // normalized alp (fp32)
  __syncthreads();

  if (t < 390) {
    const int k = t / 130;
    const int d = t - k * 130;
    const uint4* xr = (const uint4*)sXT;
    const int dbase = d * 16, dsw = d & 7;
    const float* ab = s_val + (k << 7);
    float acc = 0.f;
#pragma unroll
    for (int c = 0; c < 16; ++c) {
      const uint4 raw = xr[dbase + (c ^ dsw)];         // X[l=8c..8c+7][d]
      const float4 a0 = *(const float4*)(ab + (c << 3));
      const float4 a1 = *(const float4*)(ab + (c << 3) + 4);
      acc += a0.x * bf2f((u16)(raw.x & 0xffff));
      acc += a0.y * bf2f((u16)(raw.x >> 16));
      acc += a0.z * bf2f((u16)(raw.y & 0xffff));
      acc += a0.w * bf2f((u16)(raw.y >> 16));
      acc += a1.x * bf2f((u16)(raw.z & 0xffff));
      acc += a1.y * bf2f((u16)(raw.z >> 16));
      acc += a1.z * bf2f((u16)(raw.w & 0xffff));
      acc += a1.w * bf2f((u16)(raw.w >> 16));
    }
    const size_t o = (size_t)b * KPAD + t;
    split_store(acc, &act_hi[o], &act_lo[o]);
  }
}

// ---------------------------------------------------------------------------
// Final head (once per call).
// ---------------------------------------------------------------------------
__global__ __launch_bounds__(64) void final_head(
    const float* __restrict__ hmax, const float* __restrict__ Fe,
    const float* __restrict__ W_d1, const float* __restrict__ b_d1,
    const float* __restrict__ W_r,  const float* __restrict__ b_r,
    const float* __restrict__ W_a,
    const float* __restrict__ W_d2, const float* __restrict__ b_d2,
    float* __restrict__ out)
{
  const int b = blockIdx.x;
  const int t = threadIdx.x;
  __shared__ float sx[HDIM];
  __shared__ float sy[NFEAT];
  __shared__ float sr1[NPROJ], sr2[NPROJ];
  __shared__ float sa[2];

  for (int i = t; i < HDIM; i += 64) sx[i] = hmax[(size_t)b * HDIM + i];
  __syncthreads();

  if (t < NFEAT) {
    float acc = b_d1[t];
    const float* w = W_d1 + (size_t)t * HDIM;
    for (int i = 0; i < HDIM; ++i) acc += sx[i] * w[i];
    sy[t] = fmaxf(acc, 0.f);
  }
  __syncthreads();

  if (t < NPROJ) {
    float a1 = b_r[t], a2 = b_r[t];
    const float* w  = W_r + (size_t)t * NFEAT;
    const float* fe = Fe + (size_t)b * NFEAT;
    for (int i = 0; i < NFEAT; ++i) { a1 += sy[i] * w[i]; a2 += fe[i] * w[i]; }
    sr1[t] = (a1 > 0.f) ? a1 : 0.01f * a1;
    sr2[t] = (a2 > 0.f) ? a2 : 0.01f * a2;
  }
  __syncthreads();

  if (t == 0) {
    float a1 = 0.f, a2 = 0.f;
    for (int p = 0; p < NPROJ; ++p) {
      a1 += tanhf(sr1[p]) * W_a[p];
      a2 += tanhf(sr2[p]) * W_a[p];
    }
    const float mx = fmaxf(a1, a2);
    const float e1 = expf(a1 - mx), e2 = expf(a2 - mx);
    sa[0] = e1 / (e1 + e2);
    sa[1] = e2 / (e1 + e2);
  }
  __syncthreads();

  if (t < 2) {
    float acc = b_d2[t];
    const float* w = W_d2 + (size_t)t * NPROJ;
    for (int p = 0; p < NPROJ; ++p) {
      float s = sa[0] * sr1[p] + sa[1] * sr2[p];
      s = fmaxf(s, 0.f);
      acc += s * w[p];
    }
    out[(size_t)b * 2 + t] = acc;
  }
}

// ---------------------------------------------------------------------------
// Setup kernels (run every launch).
// ---------------------------------------------------------------------------
__global__ __launch_bounds__(256) void pack_w(
    const float* __restrict__ W_ih, const float* __restrict__ W_hh,
    const float* __restrict__ b_ih, const float* __restrict__ b_hh,
    u16* __restrict__ hi, float* __restrict__ bsum)
{
  const int idx = blockIdx.x * 256 + threadIdx.x;
  if (idx >= NGATE * KPAD) return;
  const int n = idx / KPAD;
  const int k = idx - n * KPAD;
  float v = 0.f;
  if (k < 3 * DIN)       v = W_ih[(size_t)n * (3 * DIN) + k];
  else if (k >= VOFF)    v = W_hh[(size_t)n * HDIM + (k - VOFF)];
  hi[idx] = f2bf(v);
  if (k == 0) bsum[n] = b_ih[n] + b_hh[n];
}

__global__ __launch_bounds__(256) void pack_watt(
    const float* __restrict__ W_att,   // [3][H][L]
    u16* __restrict__ hi)
{
  const int idx = blockIdx.x * 256 + threadIdx.x;   // [384][768]
  if (idx >= 384 * HDIM) return;
  const int n = idx / HDIM;          // n = k*128 + l
  const int h = idx - n * HDIM;
  const int katt = n >> 7;
  const int l = n & 127;
  hi[idx] = f2bf(W_att[((size_t)katt * HDIM + h) * LSEQ + l]);
}

// X[b][l][d] fp32 -> XT[b][d][l] bf16. One block per sample, LDS bounce.
__global__ __launch_bounds__(256) void pack_xt(
    const float* __restrict__ X, u16* __restrict__ XT)
{
  const int b = blockIdx.x;
  const int t = threadIdx.x;
  __shared__ u16 sX[XELEM];   // [l][d]
  const float* src = X + (size_t)b * XELEM;
  for (int i = t; i < XELEM; i += 256) sX[i] = f2bf(src[i]);
  __syncthreads();
  uint4* dst = (uint4*)(XT + (size_t)b * XELEM);
  for (int u = t; u < 2080; u += 256) {    // uint4 index = d*16 + blk
    const int d = u >> 4, blk = u & 15;
    const int lb = blk * 8;
    ushort4 w0, w1;
    w0.x = sX[(lb + 0) * DIN + d]; w0.y = sX[(lb + 1) * DIN + d];
    w0.z = sX[(lb + 2) * DIN + d]; w0.w = sX[(lb + 3) * DIN + d];
    w1.x = sX[(lb + 4) * DIN + d]; w1.y = sX[(lb + 5) * DIN + d];
    w1.z = sX[(lb + 6) * DIN + d]; w1.w = sX[(lb + 7) * DIN + d];
    uint4 o;
    o.x = (unsigned)w0.x | ((unsigned)w0.y << 16);
    o.y = (unsigned)w0.z | ((unsigned)w0.w << 16);
    o.z = (unsigned)w1.x | ((unsigned)w1.y << 16);
    o.w = (unsigned)w1.z | ((unsigned)w1.w << 16);
    dst[u] = o;
  }
}

__global__ __launch_bounds__(256) void init_state(
    u16* __restrict__ a0h, u16* __restrict__ a0l,
    u16* __restrict__ a1h, u16* __restrict__ a1l,
    float* __restrict__ cst, float* __restrict__ hmax)
{
  const int idx = blockIdx.x * 256 + threadIdx.x;
  if (idx < B_SZ * KPAD) { a0h[idx] = 0; a0l[idx] = 0; a1h[idx] = 0; a1l[idx] = 0; }
  if (idx < B_SZ * HDIM) { cst[idx] = 0.f; hmax[idx] = -3.4e38f; }
}

// ---------------------------------------------------------------------------
extern "C" void kernel_launch(void* const* d_in, const int* in_sizes, int n_in,
                              void* d_out, int out_size, void* d_ws, size_t ws_size,
                              hipStream_t stream) {
  const float* X     = (const float*)d_in[0];
  const float* Fe    = (const float*)d_in[1];
  const float* W_att = (const float*)d_in[2];
  const float* b_att = (const float*)d_in[3];
  const float* W_ih  = (const float*)d_in[4];
  const float* W_hh  = (const float*)d_in[5];
  const float* b_ih  = (const float*)d_in[6];
  const float* b_hh  = (const float*)d_in[7];
  const float* W_d1  = (const float*)d_in[8];
  const float* b_d1  = (const float*)d_in[9];
  const float* W_r   = (const float*)d_in[10];
  const float* b_r   = (const float*)d_in[11];
  const float* W_a   = (const float*)d_in[12];
  const float* W_d2  = (const float*)d_in[13];
  const float* b_d2  = (const float*)d_in[14];
  float* out = (float*)d_out;

  char* base = (char*)d_ws;
  size_t off = 0;
  auto alloc = [&](size_t nbytes) -> void* {
    void* p = base + off;
    off = (off + nbytes + 255) & ~(size_t)255;
    return p;
  };
  u16* act0_hi = (u16*)alloc((size_t)B_SZ * KPAD * 2);
  u16* act0_lo = (u16*)alloc((size_t)B_SZ * KPAD * 2);
  u16* act1_hi = (u16*)alloc((size_t)B_SZ * KPAD * 2);
  u16* act1_lo = (u16*)alloc((size_t)B_SZ * KPAD * 2);
  u16* wcat_hi = (u16*)alloc((size_t)NGATE * KPAD * 2);
  u16* watt_hi = (u16*)alloc((size_t)384 * HDIM * 2);
  u16* xt16    = (u16*)alloc((size_t)B_SZ * XELEM * 2);
  float* bsum  = (float*)alloc((size_t)NGATE * 4);
  float* lpart = (float*)alloc((size_t)2 * B_SZ * 384 * 4);
  float* gpart = (float*)alloc((size_t)2 * B_SZ * NGATE * 4);
  float* cst   = (float*)alloc((size_t)B_SZ * HDIM * 4);
  float* hmax  = (float*)alloc((size_t)B_SZ * HDIM * 4);

  pack_w<<<(NGATE * KPAD + 255) / 256, 256, 0, stream>>>(W_ih, W_hh, b_ih, b_hh, wcat_hi, bsum);
  pack_watt<<<(384 * HDIM + 255) / 256, 256, 0, stream>>>(W_att, watt_hi);
  pack_xt<<<B_SZ, 256, 0, stream>>>(X, xt16);
  init_state<<<(B_SZ * KPAD + 255) / 256, 256, 0, stream>>>(act0_hi, act0_lo, act1_hi, act1_lo, cst, hmax);

  float* l0 = lpart;
  float* l1 = lpart + (size_t)B_SZ * 384;
  float* g0 = gpart;
  float* g1 = gpart + (size_t)B_SZ * NGATE;

  u16 *rd_hi = act0_hi, *rd_lo = act0_lo, *wr_hi = act1_hi, *wr_lo = act1_lo;
  for (int step = 0; step < LSEQ; ++step) {
    gemm_logits_k<<<dim3(B_SZ / 32, 384 / 64, 2), 256, 0, stream>>>(
        rd_hi + VOFF, rd_lo + VOFF, watt_hi, lpart);
    softmax_v<<<B_SZ, 512, 0, stream>>>(l0, l1, b_att, xt16, rd_hi, rd_lo);
    gemm_gates_k<<<dim3(B_SZ / 64, NGATE / 128, 2), 256, 0, stream>>>(
        rd_hi, rd_lo, wcat_hi, gpart);
    lstm_update<<<(B_SZ * HDIM) / 256, 256, 0, stream>>>(
        g0, g1, bsum, cst, hmax, wr_hi, wr_lo);
    u16* th = rd_hi; rd_hi = wr_hi; wr_hi = th;
    u16* tl = rd_lo; rd_lo = wr_lo; wr_lo = tl;
  }

  final_head<<<B_SZ, 64, 0, stream>>>(hmax, Fe, W_d1, b_d1, W_r, b_r, W_a, W_d2, b_d2, out);
}

// Round 6
// 5922.059 us; speedup vs baseline: 1.7120x; 1.1009x over previous
//
#include <hip/hip_runtime.h>
#include <stdint.h>

// ---------------------------------------------------------------------------
// LstmAtt round 6: spend the accuracy budget — plain-bf16 activations (no lo
// term) in both GEMMs. Structure identical to R5 (proven 6.52 ms):
//  - gates GEMM 64x128 tile, split-K=2, 768 blocks; separate lstm_update.
//  - logits GEMM 32x64 tile, split-K=2, 384 blocks; sum folded into softmax.
//  - softmax_v with XT[b][d][l] bf16 LDS staging + XOR swizzle, vector reads.
// Error history: A-exact+Wbf16=4.9e-4, +Xbf16=9.8e-4, +act-bf16 (this) ~2e-3
// vs threshold 3.96e-3.
// Act row layout (KPAD=1184 halfs): [0..389]=v, [390..415]=0 pad, [416..1183]=h.
// ---------------------------------------------------------------------------

#define B_SZ   1024
#define LSEQ   128
#define DIN    130
#define HDIM   768
#define NFEAT  49
#define NPROJ  40
#define KPAD   1184
#define VOFF   416
#define NGATE  3072
#define XELEM  (LSEQ * DIN)   // 16640

typedef unsigned short u16;
typedef __attribute__((ext_vector_type(8))) short short8;
typedef __attribute__((ext_vector_type(4))) float f32x4;

__device__ __forceinline__ u16 f2bf(float f) {
  unsigned int u = __float_as_uint(f);
  u += 0x7FFFu + ((u >> 16) & 1u);
  return (u16)(u >> 16);
}
__device__ __forceinline__ float bf2f(u16 b) {
  return __uint_as_float(((unsigned int)b) << 16);
}

// ---------------------------------------------------------------------------
// Logits GEMM, split-K=2: Cpart[kh][1024,384] = h[1024, kh-half of 768] @ W^T.
// BM=32, BN=64, 256 thr (waves 2x2: wave tile 16x32). Grid (32,6,2)=384.
// ---------------------------------------------------------------------------
__global__ __launch_bounds__(256, 4) void gemm_logits_k(
    const u16* __restrict__ Ah,
    const u16* __restrict__ Bh, float* __restrict__ Cp)
{
  __shared__ __align__(16) u16 sAh[32 * 40];
  __shared__ __align__(16) u16 sBh[64 * 40];

  const int tid = threadIdx.x, lane = tid & 63, wid = tid >> 6;
  const int wm = (wid & 1) * 16, wn = (wid >> 1) * 32;
  const int lm = lane & 15, quad = lane >> 4;
  const int bm = blockIdx.x * 32, bn = blockIdx.y * 64;
  const int kh = blockIdx.z;
  const int kbase = kh * 384;            // halfs
  float* __restrict__ C = Cp + (size_t)kh * B_SZ * 384;

  const bool aload = tid < 128;
  const int ar = tid >> 2, ac = (tid & 3) * 8;
  const size_t a_off = (size_t)(bm + ar) * KPAD + kbase + ac;
  const size_t b_off = (size_t)(bn + ar) * HDIM + kbase + ac;

  uint4 ph, pb;
  if (aload) ph = *(const uint4*)(Ah + a_off);
  pb = *(const uint4*)(Bh + b_off);

  f32x4 acc0 = {0.f, 0.f, 0.f, 0.f}, acc1 = {0.f, 0.f, 0.f, 0.f};

  for (int kt = 0; kt < 12; ++kt) {
    if (aload) *(uint4*)&sAh[ar * 40 + ac] = ph;
    *(uint4*)&sBh[ar * 40 + ac] = pb;
    __syncthreads();
    if (kt + 1 < 12) {
      const int k0 = (kt + 1) * 32;
      if (aload) ph = *(const uint4*)(Ah + a_off + k0);
      pb = *(const uint4*)(Bh + b_off + k0);
    }
    const short8 ah = *(const short8*)&sAh[(wm + lm) * 40 + quad * 8];
    const short8 b0 = *(const short8*)&sBh[(wn + lm) * 40 + quad * 8];
    const short8 b1 = *(const short8*)&sBh[(wn + 16 + lm) * 40 + quad * 8];
    acc0 = __builtin_amdgcn_mfma_f32_16x16x32_bf16(ah, b0, acc0, 0, 0, 0);
    acc1 = __builtin_amdgcn_mfma_f32_16x16x32_bf16(ah, b1, acc1, 0, 0, 0);
    __syncthreads();
  }

  const int col = bn + wn + lm;
  const int row0 = bm + wm + quad * 4;
#pragma unroll
  for (int r = 0; r < 4; ++r) {
    C[(size_t)(row0 + r) * 384 + col]      = acc0[r];
    C[(size_t)(row0 + r) * 384 + col + 16] = acc1[r];
  }
}

// ---------------------------------------------------------------------------
// Gates GEMM, split-K=2: Gpart[kh][1024,3072] partial. BM=64, BN=128, 256 thr
// (waves 2x2: wave tile 32x64, FM=2, FN=4). Grid (16,24,2)=768 (~3/CU).
// kh=0: ktiles [0,19); kh=1: [19,37).
// ---------------------------------------------------------------------------
__global__ __launch_bounds__(256, 3) void gemm_gates_k(
    const u16* __restrict__ Ah,
    const u16* __restrict__ Wh,  float* __restrict__ Gp)
{
  __shared__ __align__(16) u16 sAh[64 * 40];
  __shared__ __align__(16) u16 sBh[128 * 40];

  const int tid = threadIdx.x, lane = tid & 63, wid = tid >> 6;
  const int wm = (wid & 1) * 32, wn = (wid >> 1) * 64;
  const int lm = lane & 15, quad = lane >> 4;
  const int bm = blockIdx.x * 64, j0 = blockIdx.y * 128;
  const int kh = blockIdx.z;
  const int kn = kh ? 18 : 19;
  const int kbase = kh * 19 * 32;        // halfs
  float* __restrict__ C = Gp + (size_t)kh * B_SZ * NGATE;

  const int ar = tid >> 2, ac = (tid & 3) * 8;   // ar in [0,64)
  const size_t a_off  = (size_t)(bm + ar) * KPAD + kbase + ac;
  const size_t b_off0 = (size_t)(j0 + ar) * KPAD + kbase + ac;
  const size_t b_off1 = (size_t)(j0 + 64 + ar) * KPAD + kbase + ac;

  uint4 ph  = *(const uint4*)(Ah + a_off);
  uint4 pb0 = *(const uint4*)(Wh + b_off0);
  uint4 pb1 = *(const uint4*)(Wh + b_off1);

  f32x4 acc[2][4];
#pragma unroll
  for (int mi = 0; mi < 2; ++mi)
#pragma unroll
    for (int ni = 0; ni < 4; ++ni) acc[mi][ni] = (f32x4){0.f, 0.f, 0.f, 0.f};

  for (int kt = 0; kt < kn; ++kt) {
    *(uint4*)&sAh[ar * 40 + ac]        = ph;
    *(uint4*)&sBh[ar * 40 + ac]        = pb0;
    *(uint4*)&sBh[(64 + ar) * 40 + ac] = pb1;
    __syncthreads();
    if (kt + 1 < kn) {
      const int k0 = (kt + 1) * 32;
      ph  = *(const uint4*)(Ah + a_off + k0);
      pb0 = *(const uint4*)(Wh + b_off0 + k0);
      pb1 = *(const uint4*)(Wh + b_off1 + k0);
    }
    short8 ah[2], bh[4];
#pragma unroll
    for (int mi = 0; mi < 2; ++mi)
      ah[mi] = *(const short8*)&sAh[(wm + mi * 16 + lm) * 40 + quad * 8];
#pragma unroll
    for (int ni = 0; ni < 4; ++ni)
      bh[ni] = *(const short8*)&sBh[(wn + ni * 16 + lm) * 40 + quad * 8];
#pragma unroll
    for (int mi = 0; mi < 2; ++mi)
#pragma unroll
      for (int ni = 0; ni < 4; ++ni)
        acc[mi][ni] = __builtin_amdgcn_mfma_f32_16x16x32_bf16(ah[mi], bh[ni], acc[mi][ni], 0, 0, 0);
    __syncthreads();
  }

#pragma unroll
  for (int mi = 0; mi < 2; ++mi)
#pragma unroll
    for (int ni = 0; ni < 4; ++ni) {
      const int col = j0 + wn + ni * 16 + lm;
      const int row0 = bm + wm + mi * 16 + quad * 4;
#pragma unroll
      for (int r = 0; r < 4; ++r)
        C[(size_t)(row0 + r) * NGATE + col] = acc[mi][ni][r];
    }
}

// ---------------------------------------------------------------------------
// LSTM pointwise: g0+g1 partials + bsum -> c,h; running max; h -> act wr (bf16).
// ---------------------------------------------------------------------------
__global__ __launch_bounds__(256) void lstm_update(
    const float* __restrict__ g0, const float* __restrict__ g1,
    const float* __restrict__ bsum,
    float* __restrict__ cst, float* __restrict__ hmax,
    u16* __restrict__ out_h)
{
  const int idx = blockIdx.x * 256 + threadIdx.x;       // B*H
  const int b = idx / HDIM;
  const int j = idx - b * HDIM;
  const size_t o0 = (size_t)b * NGATE + j;
  const float pi = g0[o0]              + g1[o0]              + bsum[j];
  const float pf = g0[o0 + HDIM]       + g1[o0 + HDIM]       + bsum[HDIM + j];
  const float pg = g0[o0 + 2 * HDIM]   + g1[o0 + 2 * HDIM]   + bsum[2 * HDIM + j];
  const float po = g0[o0 + 3 * HDIM]   + g1[o0 + 3 * HDIM]   + bsum[3 * HDIM + j];
  const float si = 1.f / (1.f + expf(-pi));
  const float sf = 1.f / (1.f + expf(-pf));
  const float so = 1.f / (1.f + expf(-po));
  const float cn = sf * cst[idx] + si * tanhf(pg);
  const float hn = so * tanhf(cn);
  cst[idx] = cn;
  hmax[idx] = fmaxf(hmax[idx], hn);
  out_h[(size_t)b * KPAD + VOFF + j] = f2bf(hn);
}

// ---------------------------------------------------------------------------
// softmax_v: logits = l0+l1+b_att; softmax per head; v = alp @ X via
// XT[b][d][l] staged to LDS with XOR-block swizzle -> vector ds_read_b128.
// Writes v (bf16) into act rd buffer.
// ---------------------------------------------------------------------------
__global__ __launch_bounds__(512, 4) void softmax_v(
    const float* __restrict__ l0, const float* __restrict__ l1,
    const float* __restrict__ b_att,
    const u16* __restrict__ XT,          // [B][130][128] bf16
    u16* __restrict__ act)
{
  const int b = blockIdx.x;
  const int t = threadIdx.x;
  __shared__ __align__(16) u16 sXT[XELEM];   // swizzled [130][128]
  __shared__ float s_val[384];
  __shared__ float s_red[512];

  {
    const uint4* src = (const uint4*)(XT + (size_t)b * XELEM);
    uint4* dst = (uint4*)sXT;
#pragma unroll
    for (int rep = 0; rep < 4; ++rep) {
      const int i = t + rep * 512;       // 0..2047
      const int d = i >> 4, blk = i & 15;
      dst[d * 16 + (blk ^ (d & 7))] = src[i];
    }
    if (t < 32) {
      const int i = 2048 + t;
      const int d = i >> 4, blk = i & 15;
      dst[d * 16 + (blk ^ (d & 7))] = src[i];
    }
  }

  float x = -3.4e38f;
  if (t < 384) {
    x = l0[(size_t)b * 384 + t] + l1[(size_t)b * 384 + t] + b_att[t];
    s_val[t] = x;
  }
  s_red[t] = x;
  __syncthreads();
#pragma unroll
  for (int off = 64; off > 0; off >>= 1) {
    float other = -3.4e38f;
    if ((t & 127) < off) other = s_red[t + off];
    __syncthreads();
    if ((t & 127) < off) s_red[t] = fmaxf(s_red[t], other);
    __syncthreads();
  }
  const float mk = s_red[t & ~127];
  __syncthreads();

  float e = 0.f;
  if (t < 384) e = expf(s_val[t] - mk);
  s_red[t] = e;
  __syncthreads();
#pragma unroll
  for (int off = 64; off > 0; off >>= 1) {
    float other = 0.f;
    if ((t & 127) < off) other = s_red[t + off];
    __syncthreads();
    if ((t & 127) < off) s_red[t] += other;
    __syncthreads();
  }
  const float sk = s_red[t & ~127];
  if (t < 384) s_val[t] = e / sk;     // normalized alp (fp32)
  __syncthreads();

  if (t < 390) {
    const int k = t / 130;
    const int d = t - k * 130;
    const uint4* xr = (const uint4*)sXT;
    const int dbase = d * 16, dsw = d & 7;
    const float* ab = s_val + (k << 7);
    float acc = 0.f;
#pragma unroll
    for (int c = 0; c < 16; ++c) {
      const uint4 raw = xr[dbase + (c ^ dsw)];         // X[l=8c..8c+7][d]
      const float4 a0 = *(const float4*)(ab + (c << 3));
      const float4 a1 = *(const float4*)(ab + (c << 3) + 4);
      acc += a0.x * bf2f((u16)(raw.x & 0xffff));
      acc += a0.y * bf2f((u16)(raw.x >> 16));
      acc += a0.z * bf2f((u16)(raw.y & 0xffff));
      acc += a0.w * bf2f((u16)(raw.y >> 16));
      acc += a1.x * bf2f((u16)(raw.z & 0xffff));
      acc += a1.y * bf2f((u16)(raw.z >> 16));
      acc += a1.z * bf2f((u16)(raw.w & 0xffff));
      acc += a1.w * bf2f((u16)(raw.w >> 16));
    }
    act[(size_t)b * KPAD + t] = f2bf(acc);
  }
}

// ---------------------------------------------------------------------------
// Final head (once per call).
// ---------------------------------------------------------------------------
__global__ __launch_bounds__(64) void final_head(
    const float* __restrict__ hmax, const float* __restrict__ Fe,
    const float* __restrict__ W_d1, const float* __restrict__ b_d1,
    const float* __restrict__ W_r,  const float* __restrict__ b_r,
    const float* __restrict__ W_a,
    const float* __restrict__ W_d2, const float* __restrict__ b_d2,
    float* __restrict__ out)
{
  const int b = blockIdx.x;
  const int t = threadIdx.x;
  __shared__ float sx[HDIM];
  __shared__ float sy[NFEAT];
  __shared__ float sr1[NPROJ], sr2[NPROJ];
  __shared__ float sa[2];

  for (int i = t; i < HDIM; i += 64) sx[i] = hmax[(size_t)b * HDIM + i];
  __syncthreads();

  if (t < NFEAT) {
    float acc = b_d1[t];
    const float* w = W_d1 + (size_t)t * HDIM;
    for (int i = 0; i < HDIM; ++i) acc += sx[i] * w[i];
    sy[t] = fmaxf(acc, 0.f);
  }
  __syncthreads();

  if (t < NPROJ) {
    float a1 = b_r[t], a2 = b_r[t];
    const float* w  = W_r + (size_t)t * NFEAT;
    const float* fe = Fe + (size_t)b * NFEAT;
    for (int i = 0; i < NFEAT; ++i) { a1 += sy[i] * w[i]; a2 += fe[i] * w[i]; }
    sr1[t] = (a1 > 0.f) ? a1 : 0.01f * a1;
    sr2[t] = (a2 > 0.f) ? a2 : 0.01f * a2;
  }
  __syncthreads();

  if (t == 0) {
    float a1 = 0.f, a2 = 0.f;
    for (int p = 0; p < NPROJ; ++p) {
      a1 += tanhf(sr1[p]) * W_a[p];
      a2 += tanhf(sr2[p]) * W_a[p];
    }
    const float mx = fmaxf(a1, a2);
    const float e1 = expf(a1 - mx), e2 = expf(a2 - mx);
    sa[0] = e1 / (e1 + e2);
    sa[1] = e2 / (e1 + e2);
  }
  __syncthreads();

  if (t < 2) {
    float acc = b_d2[t];
    const float* w = W_d2 + (size_t)t * NPROJ;
    for (int p = 0; p < NPROJ; ++p) {
      float s = sa[0] * sr1[p] + sa[1] * sr2[p];
      s = fmaxf(s, 0.f);
      acc += s * w[p];
    }
    out[(size_t)b * 2 + t] = acc;
  }
}

// ---------------------------------------------------------------------------
// Setup kernels (run every launch).
// ---------------------------------------------------------------------------
__global__ __launch_bounds__(256) void pack_w(
    const float* __restrict__ W_ih, const float* __restrict__ W_hh,
    const float* __restrict__ b_ih, const float* __restrict__ b_hh,
    u16* __restrict__ hi, float* __restrict__ bsum)
{
  const int idx = blockIdx.x * 256 + threadIdx.x;
  if (idx >= NGATE * KPAD) return;
  const int n = idx / KPAD;
  const int k = idx - n * KPAD;
  float v = 0.f;
  if (k < 3 * DIN)       v = W_ih[(size_t)n * (3 * DIN) + k];
  else if (k >= VOFF)    v = W_hh[(size_t)n * HDIM + (k - VOFF)];
  hi[idx] = f2bf(v);
  if (k == 0) bsum[n] = b_ih[n] + b_hh[n];
}

__global__ __launch_bounds__(256) void pack_watt(
    const float* __restrict__ W_att,   // [3][H][L]
    u16* __restrict__ hi)
{
  const int idx = blockIdx.x * 256 + threadIdx.x;   // [384][768]
  if (idx >= 384 * HDIM) return;
  const int n = idx / HDIM;          // n = k*128 + l
  const int h = idx - n * HDIM;
  const int katt = n >> 7;
  const int l = n & 127;
  hi[idx] = f2bf(W_att[((size_t)katt * HDIM + h) * LSEQ + l]);
}

// X[b][l][d] fp32 -> XT[b][d][l] bf16. One block per sample, LDS bounce.
__global__ __launch_bounds__(256) void pack_xt(
    const float* __restrict__ X, u16* __restrict__ XT)
{
  const int b = blockIdx.x;
  const int t = threadIdx.x;
  __shared__ u16 sX[XELEM];   // [l][d]
  const float* src = X + (size_t)b * XELEM;
  for (int i = t; i < XELEM; i += 256) sX[i] = f2bf(src[i]);
  __syncthreads();
  uint4* dst = (uint4*)(XT + (size_t)b * XELEM);
  for (int u = t; u < 2080; u += 256) {    // uint4 index = d*16 + blk
    const int d = u >> 4, blk = u & 15;
    const int lb = blk * 8;
    ushort4 w0, w1;
    w0.x = sX[(lb + 0) * DIN + d]; w0.y = sX[(lb + 1) * DIN + d];
    w0.z = sX[(lb + 2) * DIN + d]; w0.w = sX[(lb + 3) * DIN + d];
    w1.x = sX[(lb + 4) * DIN + d]; w1.y = sX[(lb + 5) * DIN + d];
    w1.z = sX[(lb + 6) * DIN + d]; w1.w = sX[(lb + 7) * DIN + d];
    uint4 o;
    o.x = (unsigned)w0.x | ((unsigned)w0.y << 16);
    o.y = (unsigned)w0.z | ((unsigned)w0.w << 16);
    o.z = (unsigned)w1.x | ((unsigned)w1.y << 16);
    o.w = (unsigned)w1.z | ((unsigned)w1.w << 16);
    dst[u] = o;
  }
}

__global__ __launch_bounds__(256) void init_state(
    u16* __restrict__ a0, u16* __restrict__ a1,
    float* __restrict__ cst, float* __restrict__ hmax)
{
  const int idx = blockIdx.x * 256 + threadIdx.x;
  if (idx < B_SZ * KPAD) { a0[idx] = 0; a1[idx] = 0; }
  if (idx < B_SZ * HDIM) { cst[idx] = 0.f; hmax[idx] = -3.4e38f; }
}

// ---------------------------------------------------------------------------
extern "C" void kernel_launch(void* const* d_in, const int* in_sizes, int n_in,
                              void* d_out, int out_size, void* d_ws, size_t ws_size,
                              hipStream_t stream) {
  const float* X     = (const float*)d_in[0];
  const float* Fe    = (const float*)d_in[1];
  const float* W_att = (const float*)d_in[2];
  const float* b_att = (const float*)d_in[3];
  const float* W_ih  = (const float*)d_in[4];
  const float* W_hh  = (const float*)d_in[5];
  const float* b_ih  = (const float*)d_in[6];
  const float* b_hh  = (const float*)d_in[7];
  const float* W_d1  = (const float*)d_in[8];
  const float* b_d1  = (const float*)d_in[9];
  const float* W_r   = (const float*)d_in[10];
  const float* b_r   = (const float*)d_in[11];
  const float* W_a   = (const float*)d_in[12];
  const float* W_d2  = (const float*)d_in[13];
  const float* b_d2  = (const float*)d_in[14];
  float* out = (float*)d_out;

  char* base = (char*)d_ws;
  size_t off = 0;
  auto alloc = [&](size_t nbytes) -> void* {
    void* p = base + off;
    off = (off + nbytes + 255) & ~(size_t)255;
    return p;
  };
  u16* act0    = (u16*)alloc((size_t)B_SZ * KPAD * 2);
  u16* act1    = (u16*)alloc((size_t)B_SZ * KPAD * 2);
  u16* wcat    = (u16*)alloc((size_t)NGATE * KPAD * 2);
  u16* watt    = (u16*)alloc((size_t)384 * HDIM * 2);
  u16* xt16    = (u16*)alloc((size_t)B_SZ * XELEM * 2);
  float* bsum  = (float*)alloc((size_t)NGATE * 4);
  float* lpart = (float*)alloc((size_t)2 * B_SZ * 384 * 4);
  float* gpart = (float*)alloc((size_t)2 * B_SZ * NGATE * 4);
  float* cst   = (float*)alloc((size_t)B_SZ * HDIM * 4);
  float* hmax  = (float*)alloc((size_t)B_SZ * HDIM * 4);

  pack_w<<<(NGATE * KPAD + 255) / 256, 256, 0, stream>>>(W_ih, W_hh, b_ih, b_hh, wcat, bsum);
  pack_watt<<<(384 * HDIM + 255) / 256, 256, 0, stream>>>(W_att, watt);
  pack_xt<<<B_SZ, 256, 0, stream>>>(X, xt16);
  init_state<<<(B_SZ * KPAD + 255) / 256, 256, 0, stream>>>(act0, act1, cst, hmax);

  float* l0 = lpart;
  float* l1 = lpart + (size_t)B_SZ * 384;
  float* g0 = gpart;
  float* g1 = gpart + (size_t)B_SZ * NGATE;

  u16 *rd = act0, *wr = act1;
  for (int step = 0; step < LSEQ; ++step) {
    gemm_logits_k<<<dim3(B_SZ / 32, 384 / 64, 2), 256, 0, stream>>>(
        rd + VOFF, watt, lpart);
    softmax_v<<<B_SZ, 512, 0, stream>>>(l0, l1, b_att, xt16, rd);
    gemm_gates_k<<<dim3(B_SZ / 64, NGATE / 128, 2), 256, 0, stream>>>(
        rd, wcat, gpart);
    lstm_update<<<(B_SZ * HDIM) / 256, 256, 0, stream>>>(
        g0, g1, bsum, cst, hmax, wr);
    u16* tt = rd; rd = wr; wr = tt;
  }

  final_head<<<B_SZ, 64, 0, stream>>>(hmax, Fe, W_d1, b_d1, W_r, b_r, W_a, W_d2, b_d2, out);
}

// Round 7
// 5401.786 us; speedup vs baseline: 1.8769x; 1.0963x over previous
//
#include <hip/hip_runtime.h>
#include <stdint.h>

// ---------------------------------------------------------------------------
// LstmAtt round 7: kill the split-K partial round-trip + launch count.
//  - gates GEMM + LSTM fused, BM=64 x BN=64 (4 gate-strips x 16 j), full K,
//    grid (16,48)=768 blocks (3.0/CU balanced), epilogue via 64x68 LDS tile.
//  - logits GEMM split-K=2 (384 blocks) unchanged; sum+b_att in softmax_v.
//  - loop order: [pre: logits+softmax on h=0] then 128x { gates_lstm;
//    logits; softmax_v } with last step's attention skipped. 388 launches.
// Act row layout (KPAD=1184 halfs): [0..389]=v, [390..415]=0 pad, [416..1183]=h.
// Error ledger: W bf16 ~5e-4, X bf16 ~5e-4, act bf16 ~0 extra; absmax 9.8e-4
// vs threshold 3.96e-3.
// ---------------------------------------------------------------------------

#define B_SZ   1024
#define LSEQ   128
#define DIN    130
#define HDIM   768
#define NFEAT  49
#define NPROJ  40
#define KPAD   1184
#define VOFF   416
#define NGATE  3072
#define KT_G   37      // KPAD/32
#define XELEM  (LSEQ * DIN)   // 16640

typedef unsigned short u16;
typedef __attribute__((ext_vector_type(8))) short short8;
typedef __attribute__((ext_vector_type(4))) float f32x4;

__device__ __forceinline__ u16 f2bf(float f) {
  unsigned int u = __float_as_uint(f);
  u += 0x7FFFu + ((u >> 16) & 1u);
  return (u16)(u >> 16);
}
__device__ __forceinline__ float bf2f(u16 b) {
  return __uint_as_float(((unsigned int)b) << 16);
}

// ---------------------------------------------------------------------------
// Logits GEMM, split-K=2: Cpart[kh][1024,384] = h[1024, kh-half of 768] @ W^T.
// BM=32, BN=64, 256 thr (waves 2x2: wave tile 16x32). Grid (32,6,2)=384.
// ---------------------------------------------------------------------------
__global__ __launch_bounds__(256, 4) void gemm_logits_k(
    const u16* __restrict__ Ah,
    const u16* __restrict__ Bh, float* __restrict__ Cp)
{
  __shared__ __align__(16) u16 sAh[32 * 40];
  __shared__ __align__(16) u16 sBh[64 * 40];

  const int tid = threadIdx.x, lane = tid & 63, wid = tid >> 6;
  const int wm = (wid & 1) * 16, wn = (wid >> 1) * 32;
  const int lm = lane & 15, quad = lane >> 4;
  const int bm = blockIdx.x * 32, bn = blockIdx.y * 64;
  const int kh = blockIdx.z;
  const int kbase = kh * 384;            // halfs
  float* __restrict__ C = Cp + (size_t)kh * B_SZ * 384;

  const bool aload = tid < 128;
  const int ar = tid >> 2, ac = (tid & 3) * 8;
  const size_t a_off = (size_t)(bm + ar) * KPAD + kbase + ac;
  const size_t b_off = (size_t)(bn + ar) * HDIM + kbase + ac;

  uint4 ph, pb;
  if (aload) ph = *(const uint4*)(Ah + a_off);
  pb = *(const uint4*)(Bh + b_off);

  f32x4 acc0 = {0.f, 0.f, 0.f, 0.f}, acc1 = {0.f, 0.f, 0.f, 0.f};

  for (int kt = 0; kt < 12; ++kt) {
    if (aload) *(uint4*)&sAh[ar * 40 + ac] = ph;
    *(uint4*)&sBh[ar * 40 + ac] = pb;
    __syncthreads();
    if (kt + 1 < 12) {
      const int k0 = (kt + 1) * 32;
      if (aload) ph = *(const uint4*)(Ah + a_off + k0);
      pb = *(const uint4*)(Bh + b_off + k0);
    }
    const short8 ah = *(const short8*)&sAh[(wm + lm) * 40 + quad * 8];
    const short8 b0 = *(const short8*)&sBh[(wn + lm) * 40 + quad * 8];
    const short8 b1 = *(const short8*)&sBh[(wn + 16 + lm) * 40 + quad * 8];
    acc0 = __builtin_amdgcn_mfma_f32_16x16x32_bf16(ah, b0, acc0, 0, 0, 0);
    acc1 = __builtin_amdgcn_mfma_f32_16x16x32_bf16(ah, b1, acc1, 0, 0, 0);
    __syncthreads();
  }

  const int col = bn + wn + lm;
  const int row0 = bm + wm + quad * 4;
#pragma unroll
  for (int r = 0; r < 4; ++r) {
    C[(size_t)(row0 + r) * 384 + col]      = acc0[r];
    C[(size_t)(row0 + r) * 384 + col + 16] = acc1[r];
  }
}

// ---------------------------------------------------------------------------
// Gates GEMM + fused LSTM. BM=64 samples x BN=64 (4 gate-strips of 16 j),
// full K (37 ktiles). 256 thr, waves 2x2 (wave tile 32x32, FM=2, FN=2).
// Grid (16,48)=768 blocks = 3.0/CU balanced. Epilogue: acc -> 64x68 fp32 LDS
// tile (union with staging) -> per-(b,j) LSTM update; h(t+1) bf16 -> out act.
// ---------------------------------------------------------------------------
__global__ __launch_bounds__(256, 4) void gates_lstm(
    const u16* __restrict__ Ah,   // act rd [B][KPAD]
    const u16* __restrict__ Wh,   // wcat [3072][KPAD], rows = gate*768+j
    const float* __restrict__ bsum,
    float* __restrict__ cst, float* __restrict__ hmax,
    u16* __restrict__ out_h)      // act wr (h section written)
{
  __shared__ __align__(16) char smem[64 * 68 * 4];   // 17408 B union
  u16* sA = (u16*)smem;                // 64*40 halfs = 5120 B
  u16* sB = (u16*)(smem + 5120);       // 64*40 halfs
  float* tile = (float*)smem;          // epilogue: 64 x 68 fp32

  const int tid = threadIdx.x, lane = tid & 63, wid = tid >> 6;
  const int wm = (wid & 1) * 32, wn = (wid >> 1) * 32;
  const int lm = lane & 15, quad = lane >> 4;
  const int bm = blockIdx.x * 64, j0 = blockIdx.y * 16;

  const int ar = tid >> 2, ac = (tid & 3) * 8;   // ar in [0,64)
  const size_t a_off = (size_t)(bm + ar) * KPAD + ac;
  const int nrow = (ar >> 4) * HDIM + j0 + (ar & 15);   // gate*768 + j
  const size_t b_off = (size_t)nrow * KPAD + ac;

  uint4 pa = *(const uint4*)(Ah + a_off);
  uint4 pb = *(const uint4*)(Wh + b_off);

  f32x4 acc[2][2];
#pragma unroll
  for (int mi = 0; mi < 2; ++mi)
#pragma unroll
    for (int ni = 0; ni < 2; ++ni) acc[mi][ni] = (f32x4){0.f, 0.f, 0.f, 0.f};

  for (int kt = 0; kt < KT_G; ++kt) {
    *(uint4*)&sA[ar * 40 + ac] = pa;
    *(uint4*)&sB[ar * 40 + ac] = pb;
    __syncthreads();
    if (kt + 1 < KT_G) {
      const int k0 = (kt + 1) * 32;
      pa = *(const uint4*)(Ah + a_off + k0);
      pb = *(const uint4*)(Wh + b_off + k0);
    }
    short8 af[2], bf[2];
#pragma unroll
    for (int mi = 0; mi < 2; ++mi)
      af[mi] = *(const short8*)&sA[(wm + mi * 16 + lm) * 40 + quad * 8];
#pragma unroll
    for (int ni = 0; ni < 2; ++ni)
      bf[ni] = *(const short8*)&sB[(wn + ni * 16 + lm) * 40 + quad * 8];
#pragma unroll
    for (int mi = 0; mi < 2; ++mi)
#pragma unroll
      for (int ni = 0; ni < 2; ++ni)
        acc[mi][ni] = __builtin_amdgcn_mfma_f32_16x16x32_bf16(af[mi], bf[ni], acc[mi][ni], 0, 0, 0);
    __syncthreads();
  }

  // ---- epilogue: acc -> LDS tile (cols = gate*16 + jj) ----
#pragma unroll
  for (int mi = 0; mi < 2; ++mi)
#pragma unroll
    for (int ni = 0; ni < 2; ++ni) {
      const int c = wn + ni * 16 + lm;
#pragma unroll
      for (int r = 0; r < 4; ++r)
        tile[(wm + mi * 16 + quad * 4 + r) * 68 + c] = acc[mi][ni][r];
    }
  __syncthreads();

#pragma unroll
  for (int i = 0; i < 4; ++i) {
    const int lin = tid + 256 * i;        // 64 rows x 16 jj
    const int row = lin >> 4, jj = lin & 15;
    const int b = bm + row, j = j0 + jj;
    const float* tr = tile + row * 68;
    const float pi = tr[jj]      + bsum[j];
    const float pf = tr[16 + jj] + bsum[HDIM + j];
    const float pg = tr[32 + jj] + bsum[2 * HDIM + j];
    const float po = tr[48 + jj] + bsum[3 * HDIM + j];
    const float si = 1.f / (1.f + expf(-pi));
    const float sf = 1.f / (1.f + expf(-pf));
    const float so = 1.f / (1.f + expf(-po));
    const size_t cidx = (size_t)b * HDIM + j;
    const float cn = sf * cst[cidx] + si * tanhf(pg);
    const float hn = so * tanhf(cn);
    cst[cidx] = cn;
    hmax[cidx] = fmaxf(hmax[cidx], hn);
    out_h[(size_t)b * KPAD + VOFF + j] = f2bf(hn);
  }
}

// ---------------------------------------------------------------------------
// softmax_v: logits = l0+l1+b_att; softmax per head; v = alp @ X via
// XT[b][d][l] staged to LDS with XOR-block swizzle -> vector ds_read_b128.
// Writes v (bf16) into the act buffer it is given.
// ---------------------------------------------------------------------------
__global__ __launch_bounds__(512, 4) void softmax_v(
    const float* __restrict__ l0, const float* __restrict__ l1,
    const float* __restrict__ b_att,
    const u16* __restrict__ XT,          // [B][130][128] bf16
    u16* __restrict__ act)
{
  const int b = blockIdx.x;
  const int t = threadIdx.x;
  __shared__ __align__(16) u16 sXT[XELEM];   // swizzled [130][128]
  __shared__ float s_val[384];
  __shared__ float s_red[512];

  {
    const uint4* src = (const uint4*)(XT + (size_t)b * XELEM);
    uint4* dst = (uint4*)sXT;
#pragma unroll
    for (int rep = 0; rep < 4; ++rep) {
      const int i = t + rep * 512;       // 0..2047
      const int d = i >> 4, blk = i & 15;
      dst[d * 16 + (blk ^ (d & 7))] = src[i];
    }
    if (t < 32) {
      const int i = 2048 + t;
      const int d = i >> 4, blk = i & 15;
      dst[d * 16 + (blk ^ (d & 7))] = src[i];
    }
  }

  float x = -3.4e38f;
  if (t < 384) {
    x = l0[(size_t)b * 384 + t] + l1[(size_t)b * 384 + t] + b_att[t];
    s_val[t] = x;
  }
  s_red[t] = x;
  __syncthreads();
#pragma unroll
  for (int off = 64; off > 0; off >>= 1) {
    float other = -3.4e38f;
    if ((t & 127) < off) other = s_red[t + off];
    __syncthreads();
    if ((t & 127) < off) s_red[t] = fmaxf(s_red[t], other);
    __syncthreads();
  }
  const float mk = s_red[t & ~127];
  __syncthreads();

  float e = 0.f;
  if (t < 384) e = expf(s_val[t] - mk);
  s_red[t] = e;
  __syncthreads();
#pragma unroll
  for (int off = 64; off > 0; off >>= 1) {
    float other = 0.f;
    if ((t & 127) < off) other = s_red[t + off];
    __syncthreads();
    if ((t & 127) < off) s_red[t] += other;
    __syncthreads();
  }
  const float sk = s_red[t & ~127];
  if (t < 384) s_val[t] = e / sk;     // normalized alp (fp32)
  __syncthreads();

  if (t < 390) {
    const int k = t / 130;
    const int d = t - k * 130;
    const uint4* xr = (const uint4*)sXT;
    const int dbase = d * 16, dsw = d & 7;
    const float* ab = s_val + (k << 7);
    float acc = 0.f;
#pragma unroll
    for (int c = 0; c < 16; ++c) {
      const uint4 raw = xr[dbase + (c ^ dsw)];         // X[l=8c..8c+7][d]
      const float4 a0 = *(const float4*)(ab + (c << 3));
      const float4 a1 = *(const float4*)(ab + (c << 3) + 4);
      acc += a0.x * bf2f((u16)(raw.x & 0xffff));
      acc += a0.y * bf2f((u16)(raw.x >> 16));
      acc += a0.z * bf2f((u16)(raw.y & 0xffff));
      acc += a0.w * bf2f((u16)(raw.y >> 16));
      acc += a1.x * bf2f((u16)(raw.z & 0xffff));
      acc += a1.y * bf2f((u16)(raw.z >> 16));
      acc += a1.z * bf2f((u16)(raw.w & 0xffff));
      acc += a1.w * bf2f((u16)(raw.w >> 16));
    }
    act[(size_t)b * KPAD + t] = f2bf(acc);
  }
}

// ---------------------------------------------------------------------------
// Final head (once per call).
// ---------------------------------------------------------------------------
__global__ __launch_bounds__(64) void final_head(
    const float* __restrict__ hmax, const float* __restrict__ Fe,
    const float* __restrict__ W_d1, const float* __restrict__ b_d1,
    const float* __restrict__ W_r,  const float* __restrict__ b_r,
    const float* __restrict__ W_a,
    const float* __restrict__ W_d2, const float* __restrict__ b_d2,
    float* __restrict__ out)
{
  const int b = blockIdx.x;
  const int t = threadIdx.x;
  __shared__ float sx[HDIM];
  __shared__ float sy[NFEAT];
  __shared__ float sr1[NPROJ], sr2[NPROJ];
  __shared__ float sa[2];

  for (int i = t; i < HDIM; i += 64) sx[i] = hmax[(size_t)b * HDIM + i];
  __syncthreads();

  if (t < NFEAT) {
    float acc = b_d1[t];
    const float* w = W_d1 + (size_t)t * HDIM;
    for (int i = 0; i < HDIM; ++i) acc += sx[i] * w[i];
    sy[t] = fmaxf(acc, 0.f);
  }
  __syncthreads();

  if (t < NPROJ) {
    float a1 = b_r[t], a2 = b_r[t];
    const float* w  = W_r + (size_t)t * NFEAT;
    const float* fe = Fe + (size_t)b * NFEAT;
    for (int i = 0; i < NFEAT; ++i) { a1 += sy[i] * w[i]; a2 += fe[i] * w[i]; }
    sr1[t] = (a1 > 0.f) ? a1 : 0.01f * a1;
    sr2[t] = (a2 > 0.f) ? a2 : 0.01f * a2;
  }
  __syncthreads();

  if (t == 0) {
    float a1 = 0.f, a2 = 0.f;
    for (int p = 0; p < NPROJ; ++p) {
      a1 += tanhf(sr1[p]) * W_a[p];
      a2 += tanhf(sr2[p]) * W_a[p];
    }
    const float mx = fmaxf(a1, a2);
    const float e1 = expf(a1 - mx), e2 = expf(a2 - mx);
    sa[0] = e1 / (e1 + e2);
    sa[1] = e2 / (e1 + e2);
  }
  __syncthreads();

  if (t < 2) {
    float acc = b_d2[t];
    const float* w = W_d2 + (size_t)t * NPROJ;
    for (int p = 0; p < NPROJ; ++p) {
      float s = sa[0] * sr1[p] + sa[1] * sr2[p];
      s = fmaxf(s, 0.f);
      acc += s * w[p];
    }
    out[(size_t)b * 2 + t] = acc;
  }
}

// ---------------------------------------------------------------------------
// Setup kernels (run every launch).
// ---------------------------------------------------------------------------
__global__ __launch_bounds__(256) void pack_w(
    const float* __restrict__ W_ih, const float* __restrict__ W_hh,
    const float* __restrict__ b_ih, const float* __restrict__ b_hh,
    u16* __restrict__ hi, float* __restrict__ bsum)
{
  const int idx = blockIdx.x * 256 + threadIdx.x;
  if (idx >= NGATE * KPAD) return;
  const int n = idx / KPAD;
  const int k = idx - n * KPAD;
  float v = 0.f;
  if (k < 3 * DIN)       v = W_ih[(size_t)n * (3 * DIN) + k];
  else if (k >= VOFF)    v = W_hh[(size_t)n * HDIM + (k - VOFF)];
  hi[idx] = f2bf(v);
  if (k == 0) bsum[n] = b_ih[n] + b_hh[n];
}

__global__ __launch_bounds__(256) void pack_watt(
    const float* __restrict__ W_att,   // [3][H][L]
    u16* __restrict__ hi)
{
  const int idx = blockIdx.x * 256 + threadIdx.x;   // [384][768]
  if (idx >= 384 * HDIM) return;
  const int n = idx / HDIM;          // n = k*128 + l
  const int h = idx - n * HDIM;
  const int katt = n >> 7;
  const int l = n & 127;
  hi[idx] = f2bf(W_att[((size_t)katt * HDIM + h) * LSEQ + l]);
}

// X[b][l][d] fp32 -> XT[b][d][l] bf16. One block per sample, LDS bounce.
__global__ __launch_bounds__(256) void pack_xt(
    const float* __restrict__ X, u16* __restrict__ XT)
{
  const int b = blockIdx.x;
  const int t = threadIdx.x;
  __shared__ u16 sX[XELEM];   // [l][d]
  const float* src = X + (size_t)b * XELEM;
  for (int i = t; i < XELEM; i += 256) sX[i] = f2bf(src[i]);
  __syncthreads();
  uint4* dst = (uint4*)(XT + (size_t)b * XELEM);
  for (int u = t; u < 2080; u += 256) {    // uint4 index = d*16 + blk
    const int d = u >> 4, blk = u & 15;
    const int lb = blk * 8;
    ushort4 w0, w1;
    w0.x = sX[(lb + 0) * DIN + d]; w0.y = sX[(lb + 1) * DIN + d];
    w0.z = sX[(lb + 2) * DIN + d]; w0.w = sX[(lb + 3) * DIN + d];
    w1.x = sX[(lb + 4) * DIN + d]; w1.y = sX[(lb + 5) * DIN + d];
    w1.z = sX[(lb + 6) * DIN + d]; w1.w = sX[(lb + 7) * DIN + d];
    uint4 o;
    o.x = (unsigned)w0.x | ((unsigned)w0.y << 16);
    o.y = (unsigned)w0.z | ((unsigned)w0.w << 16);
    o.z = (unsigned)w1.x | ((unsigned)w1.y << 16);
    o.w = (unsigned)w1.z | ((unsigned)w1.w << 16);
    dst[u] = o;
  }
}

__global__ __launch_bounds__(256) void init_state(
    u16* __restrict__ a0, u16* __restrict__ a1,
    float* __restrict__ cst, float* __restrict__ hmax)
{
  const int idx = blockIdx.x * 256 + threadIdx.x;
  if (idx < B_SZ * KPAD) { a0[idx] = 0; a1[idx] = 0; }
  if (idx < B_SZ * HDIM) { cst[idx] = 0.f; hmax[idx] = -3.4e38f; }
}

// ---------------------------------------------------------------------------
extern "C" void kernel_launch(void* const* d_in, const int* in_sizes, int n_in,
                              void* d_out, int out_size, void* d_ws, size_t ws_size,
                              hipStream_t stream) {
  const float* X     = (const float*)d_in[0];
  const float* Fe    = (const float*)d_in[1];
  const float* W_att = (const float*)d_in[2];
  const float* b_att = (const float*)d_in[3];
  const float* W_ih  = (const float*)d_in[4];
  const float* W_hh  = (const float*)d_in[5];
  const float* b_ih  = (const float*)d_in[6];
  const float* b_hh  = (const float*)d_in[7];
  const float* W_d1  = (const float*)d_in[8];
  const float* b_d1  = (const float*)d_in[9];
  const float* W_r   = (const float*)d_in[10];
  const float* b_r   = (const float*)d_in[11];
  const float* W_a   = (const float*)d_in[12];
  const float* W_d2  = (const float*)d_in[13];
  const float* b_d2  = (const float*)d_in[14];
  float* out = (float*)d_out;

  char* base = (char*)d_ws;
  size_t off = 0;
  auto alloc = [&](size_t nbytes) -> void* {
    void* p = base + off;
    off = (off + nbytes + 255) & ~(size_t)255;
    return p;
  };
  u16* act0    = (u16*)alloc((size_t)B_SZ * KPAD * 2);
  u16* act1    = (u16*)alloc((size_t)B_SZ * KPAD * 2);
  u16* wcat    = (u16*)alloc((size_t)NGATE * KPAD * 2);
  u16* watt    = (u16*)alloc((size_t)384 * HDIM * 2);
  u16* xt16    = (u16*)alloc((size_t)B_SZ * XELEM * 2);
  float* bsum  = (float*)alloc((size_t)NGATE * 4);
  float* lpart = (float*)alloc((size_t)2 * B_SZ * 384 * 4);
  float* cst   = (float*)alloc((size_t)B_SZ * HDIM * 4);
  float* hmax  = (float*)alloc((size_t)B_SZ * HDIM * 4);

  pack_w<<<(NGATE * KPAD + 255) / 256, 256, 0, stream>>>(W_ih, W_hh, b_ih, b_hh, wcat, bsum);
  pack_watt<<<(384 * HDIM + 255) / 256, 256, 0, stream>>>(W_att, watt);
  pack_xt<<<B_SZ, 256, 0, stream>>>(X, xt16);
  init_state<<<(B_SZ * KPAD + 255) / 256, 256, 0, stream>>>(act0, act1, cst, hmax);

  float* l0 = lpart;
  float* l1 = lpart + (size_t)B_SZ * 384;

  // step-0 attention on h=0 (logits = b_att): fill act0.v
  gemm_logits_k<<<dim3(B_SZ / 32, 384 / 64, 2), 256, 0, stream>>>(act0 + VOFF, watt, lpart);
  softmax_v<<<B_SZ, 512, 0, stream>>>(l0, l1, b_att, xt16, act0);

  u16 *rd = act0, *wr = act1;
  for (int step = 0; step < LSEQ; ++step) {
    gates_lstm<<<dim3(B_SZ / 64, HDIM / 16), 256, 0, stream>>>(
        rd, wcat, bsum, cst, hmax, wr);
    if (step + 1 < LSEQ) {
      gemm_logits_k<<<dim3(B_SZ / 32, 384 / 64, 2), 256, 0, stream>>>(wr + VOFF, watt, lpart);
      softmax_v<<<B_SZ, 512, 0, stream>>>(l0, l1, b_att, xt16, wr);
    }
    u16* tt = rd; rd = wr; wr = tt;
  }

  final_head<<<B_SZ, 64, 0, stream>>>(hmax, Fe, W_d1, b_d1, W_r, b_r, W_a, W_d2, b_d2, out);
}